// Round 1
// 257.388 us; speedup vs baseline: 1.0395x; 1.0395x over previous
//
#include <hip/hip_runtime.h>
#include <hip/hip_bf16.h>

typedef __bf16 bf16x8 __attribute__((ext_vector_type(8)));
typedef __bf16 bf16x4 __attribute__((ext_vector_type(4)));
typedef float floatx4 __attribute__((ext_vector_type(4)));

// Async global->LDS DMA, 16 B per lane. Dest is wave-uniform base + lane*16
// (HW takes firstlane of the LDS pointer); source is per-lane.
__device__ __forceinline__ void async16(void* lds, const void* g) {
  __builtin_amdgcn_global_load_lds(
      (const __attribute__((address_space(1))) unsigned int*)g,
      (__attribute__((address_space(3))) unsigned int*)lds, 16, 0, 0);
}

// Fused preprocess: x->bf16 (blocks 0..2047), K->bf16 (2048..3071),
// V->Vt bf16 transpose (3072..4095), lsum zero (block 4096).
__global__ __launch_bounds__(256) void preprocess_kernel(
    const float* __restrict__ x, const float* __restrict__ Kp,
    const float* __restrict__ V, __bf16* __restrict__ xb,
    __bf16* __restrict__ Kb, __bf16* __restrict__ Vt,
    float* __restrict__ lsum) {
  const int b = blockIdx.x;
  const int t = threadIdx.x;
  if (b < 2048) {
#pragma unroll
    for (int k = 0; k < 4; ++k) {
      const int i = b * 1024 + k * 256 + t;
      float4 v = ((const float4*)x)[i];
      bf16x4 o = {(__bf16)v.x, (__bf16)v.y, (__bf16)v.z, (__bf16)v.w};
      ((bf16x4*)xb)[i] = o;
    }
  } else if (b < 3072) {
#pragma unroll
    for (int k = 0; k < 4; ++k) {
      const int i = (b - 2048) * 1024 + k * 256 + t;
      float4 v = ((const float4*)Kp)[i];
      bf16x4 o = {(__bf16)v.x, (__bf16)v.y, (__bf16)v.z, (__bf16)v.w};
      ((bf16x4*)Kb)[i] = o;
    }
  } else if (b < 4096) {
    __shared__ float tile[64][65];
    const int bb = b - 3072;
    const int bx = bb & 63, by = bb >> 6;
    for (int i = t; i < 64 * 64; i += 256) {
      const int r = i >> 6, c = i & 63;
      tile[r][c] = V[(size_t)(bx * 64 + r) * 1024 + by * 64 + c];
    }
    __syncthreads();
    for (int i = t; i < 64 * 64; i += 256) {
      const int r = i >> 6, c = i & 63;
      Vt[(size_t)(by * 64 + r) * 4096 + bx * 64 + c] = (__bf16)tile[c][r];
    }
  } else {
#pragma unroll
    for (int k = 0; k < 8; ++k)
      ((floatx4*)lsum)[k * 256 + t] = floatx4{0.f, 0.f, 0.f, 0.f};
  }
}

// C = A (MxK bf16, k-contig) x B (N rows of K bf16, k-contig). 128x128 tile, BK=64.
// m97-style staging: global_load_lds_dwordx4 direct to LDS (no VGPR round-trip,
// no ds_write on the critical path). Single LDS buffer, 2 barriers per K-step;
// the first __syncthreads' vmcnt(0) drain lands the async loads before ds_read.
// LDS: XOR-swizzled; 16-B unit (row m, k-chunk q in 0..7) at unit 8m + (q^(m&7)).
//  - LDS dest is LINEAR (thread t -> byte t*16 + r*4096: wave-uniform base +
//    lane*16, as global_load_lds requires); the swizzle is applied on the
//    GLOBAL source instead: thread t fetches row (t>>3), chunk (t&7)^((t>>3)&7)
//    (pre-swizzled-global pattern, so the LDS image is identical to before).
//  - fragment reads conflict-free (verified earlier: SQ_LDS_BANK_CONFLICT = 0).
//  - k-slice 1 address = slice-0 address ^ 64.
// Flat-1D grid + XCD swizzle (id%8 = XCD): blocks sharing an A m-tile share an XCD.
// MODE 0: P = exp(min(dot/32,30)) -> bf16 Cb + fused row-sum atomicAdd into lsum.
// MODE 1: out = dot / lsum[m] -> fp32 Cf.
template <int MODE, int KS, int NS>
__global__ __launch_bounds__(256) void gemm_kernel(const __bf16* __restrict__ A,
                                                   const __bf16* __restrict__ B,
                                                   __bf16* __restrict__ Cb,
                                                   float* __restrict__ Cf,
                                                   float* __restrict__ lsum) {
  constexpr int BK = 64;
  __shared__ __bf16 As[128 * BK];  // 16 KiB
  __shared__ __bf16 Bs[128 * BK];  // 16 KiB
  const int t = threadIdx.x;
  const int lane = t & 63;
  const int w = t >> 6;
  const int wr = w >> 1, wc = w & 1;

  const int id = blockIdx.x;
  const int g = id & 7;
  const int s = id >> 3;
  const int mt = g * 8 + (s & 7);
  const int nt = s >> 3;
  const int m0 = mt * 128;
  const int n0 = nt * 128;

  const __bf16* Ab = A + (size_t)m0 * KS;
  const __bf16* Bb = B + (size_t)n0 * KS;

  floatx4 acc[4][4] = {};

  // staging: thread t -> row r*32 + (t>>3), global chunk (t&7)^((t>>3)&7),
  // LDS dest byte t*16 + r*4096 (linear).
  const int mA = t >> 3;
  const int qs = (t & 7) ^ (mA & 7);
  const __bf16* aP = Ab + (size_t)mA * KS + qs * 8;
  const __bf16* bP = Bb + (size_t)mA * KS + qs * 8;
  char* dA = (char*)As + t * 16;
  char* dB = (char*)Bs + t * 16;

  // fragment read offset (k-slice 0)
  const int rl = lane & 15;
  const int qq = lane >> 4;
  const int fo = rl * 128 + ((qq ^ (rl & 7)) << 4);

  for (int k0 = 0; k0 < KS; k0 += BK) {
    // async stage tile k0 directly into LDS (8x global_load_lds_dwordx4)
#pragma unroll
    for (int r = 0; r < 4; ++r) {
      async16(dA + r * 4096, aP + (size_t)r * 32 * KS + k0);
      async16(dB + r * 4096, bP + (size_t)r * 32 * KS + k0);
    }
    __syncthreads();  // vmcnt(0)+lgkmcnt(0) drain: LDS image complete

    bf16x8 aF[4], bF[4];
#pragma unroll
    for (int i = 0; i < 4; ++i) {
      aF[i] = *(const bf16x8*)((const char*)As + wr * 8192 + i * 2048 + fo);
      bF[i] = *(const bf16x8*)((const char*)Bs + wc * 8192 + i * 2048 + fo);
    }
#pragma unroll
    for (int i = 0; i < 4; ++i)
#pragma unroll
      for (int j = 0; j < 4; ++j)
        acc[i][j] = __builtin_amdgcn_mfma_f32_16x16x32_bf16(aF[i], bF[j], acc[i][j], 0, 0, 0);
#pragma unroll
    for (int i = 0; i < 4; ++i) {
      aF[i] = *(const bf16x8*)((const char*)As + wr * 8192 + i * 2048 + (fo ^ 64));
      bF[i] = *(const bf16x8*)((const char*)Bs + wc * 8192 + i * 2048 + (fo ^ 64));
    }
#pragma unroll
    for (int i = 0; i < 4; ++i)
#pragma unroll
      for (int j = 0; j < 4; ++j)
        acc[i][j] = __builtin_amdgcn_mfma_f32_16x16x32_bf16(aF[i], bF[j], acc[i][j], 0, 0, 0);
    __syncthreads();  // protect LDS before next iteration's async stores land
  }

  // C/D layout: col = lane&15, row = (lane>>4)*4 + reg
  const int cm = wr * 64 + ((lane >> 4) << 2);
  const int cn = wc * 64 + (lane & 15);
  if (MODE == 0) {
#pragma unroll
    for (int i = 0; i < 4; ++i)
#pragma unroll
      for (int r = 0; r < 4; ++r) {
        const int m = m0 + cm + i * 16 + r;
        float rs = 0.f;
#pragma unroll
        for (int j = 0; j < 4; ++j) {
          const float e = __expf(fminf(acc[i][j][r] * 0.03125f, 30.0f));
          rs += e;
          Cb[(size_t)m * NS + n0 + cn + j * 16] = (__bf16)e;
        }
        rs += __shfl_xor(rs, 1, 64);
        rs += __shfl_xor(rs, 2, 64);
        rs += __shfl_xor(rs, 4, 64);
        rs += __shfl_xor(rs, 8, 64);
        if ((lane & 15) == 0) atomicAdd(&lsum[m], rs);
      }
  } else {
#pragma unroll
    for (int i = 0; i < 4; ++i)
#pragma unroll
      for (int r = 0; r < 4; ++r) {
        const int m = m0 + cm + i * 16 + r;
        const float inv = 1.0f / lsum[m];
#pragma unroll
        for (int j = 0; j < 4; ++j)
          Cf[(size_t)m * NS + n0 + cn + j * 16] = acc[i][j][r] * inv;
      }
  }
}

extern "C" void kernel_launch(void* const* d_in, const int* in_sizes, int n_in,
                              void* d_out, int out_size, void* d_ws, size_t ws_size,
                              hipStream_t stream) {
  const float* x = (const float*)d_in[0];  // [8192][1024] fp32
  const float* K = (const float*)d_in[1];  // [4096][1024] fp32
  const float* V = (const float*)d_in[2];  // [4096][1024] fp32
  float* out = (float*)d_out;              // [8192][1024] fp32

  char* ws = (char*)d_ws;
  __bf16* xb = (__bf16*)ws;                        // 16 MiB
  __bf16* Kb = (__bf16*)(ws + (16u << 20));        // 8 MiB
  __bf16* Vt = (__bf16*)(ws + (24u << 20));        // 8 MiB
  __bf16* P  = (__bf16*)(ws + (32u << 20));        // 64 MiB
  float*  l  = (float*)(ws + (96u << 20));         // 32 KiB

  preprocess_kernel<<<4097, 256, 0, stream>>>(x, K, V, xb, Kb, Vt, l);
  // P = exp(xb @ Kb^T / 32), fused row sums  (M=8192 N=4096 K=1024), 2048 blocks
  gemm_kernel<0, 1024, 4096><<<2048, 256, 0, stream>>>(xb, Kb, P, nullptr, l);
  // out = (P @ Vt-rows) / l  (M=8192 N=1024 K=4096), 512 blocks
  gemm_kernel<1, 4096, 1024><<<512, 256, 0, stream>>>(P, Vt, nullptr, out, l);
}